// Round 4
// baseline (177.391 us; speedup 1.0000x reference)
//
#include <hip/hip_runtime.h>

typedef __bf16 bf16;
typedef short s16x8 __attribute__((ext_vector_type(8)));   // 8 bf16 bit-patterns for MFMA frags
typedef __bf16 b16x8 __attribute__((ext_vector_type(8)));  // 8 bf16 for scalar convert paths
typedef float f32x4 __attribute__((ext_vector_type(4)));

#define B_   4096
#define L_   50
#define SH   72               // H row stride (bf16): 64 + 8 pad (2-way bank alias, free)

// ws layout, bf16 elems. Frag-major matrices: frag f = kt*4+nt is a contiguous
// 512-elem (1 KB) block; elem = f*512 + lane*8 + j -> W[k=kt*32+(lane>>4)*8+j][n=nt*16+(lane&15)].
#define OFF_W1F  0            // gv_w1  frag-major, K=128 (16 frags)
#define OFF_W2F  8192         // gv_w2  frag-major, K=64 (8 frags)
#define OFF_W3F  12288        // gv_w3  frag-major
#define OFF_WCF  16384        // (gv_w3 @ att_w1_top) frag-major
#define OFF_A2F  20480        // att_w2 frag-major
#define OFF_R1T  24576        // [64][128] wr1^T row-major (combine tail per-lane dots)
#define OFF_R2T  32768        // [64][64]  wr2^T row-major
#define WT_TOTAL 36864
// byte offsets in ws:
#define BIAS1P_BYTE 73728     // float[64]        att_b1 + gv_b3 @ att_w1_top
#define CQ_BYTE     73984     // float[4096][64]  q_b @ A1_bot  (bias1p added in dense)
#define EU16_BYTE   1122560   // bf16[100000][64] embed_u pre-converted (RNE, same as mkfrag)
#define ER16_BYTE   13922560  // bf16[5][64]      embed_r pre-converted
#define WS_NEED     13923200

#define PREP_W_BLOCKS 145     // ceil((WT_TOTAL+64)/256)
#define CQ_BLOCKS     32      // 4096 items / (4 waves x 32 items) -- MFMA cq
#define CONV_THREADS  800040  // 100000*64/8 + 5*64/8
#define CONV_BLOCKS   3126    // ceil(CONV_THREADS/256)

__device__ __forceinline__ unsigned short f2b(float f) {
    __bf16 h = (__bf16)f;
    return __builtin_bit_cast(unsigned short, h);
}
__device__ __forceinline__ unsigned pack2(float a, float b) {
    return (unsigned)f2b(a) | ((unsigned)f2b(b) << 16);
}
__device__ __forceinline__ s16x8 mkfrag(float4 a, float4 b) {
    union { s16x8 v; unsigned u[4]; } r;
    r.u[0] = pack2(a.x, a.y); r.u[1] = pack2(a.z, a.w);
    r.u[2] = pack2(b.x, b.y); r.u[3] = pack2(b.z, b.w);
    return r.v;
}
__device__ __forceinline__ f32x4 mfma16(s16x8 a, s16x8 b, f32x4 c) {
    return __builtin_amdgcn_mfma_f32_16x16x32_bf16(a, b, c, 0, 0, 0);
}
__device__ __forceinline__ s16x8 ntload16(const bf16* p) {   // streaming gather: bypass L1 reuse
    return __builtin_nontemporal_load((const s16x8*)p);
}

// -------- prep (single launch): frag-major weights + bias1' + MFMA cq + bf16 embed tables -------
extern "C" __global__ void prep_all(const float* __restrict__ w1, const float* __restrict__ w2,
                                    const float* __restrict__ w3, const float* __restrict__ a1,
                                    const float* __restrict__ a2, const float* __restrict__ r1,
                                    const float* __restrict__ r2, const float* __restrict__ gb3,
                                    const float* __restrict__ ab1,
                                    const int* __restrict__ nodes_v, const float* __restrict__ embed_i,
                                    const float* __restrict__ embed_u, const float* __restrict__ embed_r,
                                    bf16* __restrict__ wt, float* __restrict__ bias1p,
                                    float* __restrict__ cq,
                                    bf16* __restrict__ eu16, bf16* __restrict__ er16)
{
    if (blockIdx.x >= PREP_W_BLOCKS + CQ_BLOCKS) {
        // bf16 conversion of the gather tables (identical RNE rounding to the old mkfrag path)
        long t = (long)(blockIdx.x - PREP_W_BLOCKS - CQ_BLOCKS) * 256 + threadIdx.x;
        if (t < 800000) {
            const float* s = embed_u + t * 8;
            float4 a = *(const float4*)s, b = *(const float4*)(s + 4);
            *(s16x8*)(eu16 + t * 8) = mkfrag(a, b);
        } else if (t < CONV_THREADS) {
            long r = (t - 800000) * 8;
            const float* s = embed_r + r;
            float4 a = *(const float4*)s, b = *(const float4*)(s + 4);
            *(s16x8*)(er16 + r) = mkfrag(a, b);
        }
        return;
    }
    if (blockIdx.x >= PREP_W_BLOCKS) {
        // cq[i][n] = q_i @ A1_bot via MFMA: wave = 32 items (2 A-tiles), K=64, N=64.
        // B-frags built inline from a1 (L2-hot scalar loads) -> no dependence on wt (no race).
        int wv   = (blockIdx.x - PREP_W_BLOCKS) * 4 + (threadIdx.x >> 6);   // 0..127
        int lane = threadIdx.x & 63, m = lane & 15, quad = lane >> 4;
        int base = wv * 32;
        int i0 = base + m, i1 = base + 16 + m;
        int v0 = nodes_v[i0], v1 = nodes_v[i1];

        s16x8 bfr[8];
#pragma unroll
        for (int kt = 0; kt < 2; ++kt)
#pragma unroll
            for (int nt = 0; nt < 4; ++nt) {
                const float* src = a1 + (64 + kt * 32 + quad * 8) * 64 + nt * 16 + m;
                union { s16x8 v; unsigned u[4]; } fr;
#pragma unroll
                for (int jj = 0; jj < 4; ++jj)
                    fr.u[jj] = pack2(src[(2 * jj) * 64], src[(2 * jj + 1) * 64]);
                bfr[kt * 4 + nt] = fr.v;
            }

        f32x4 ac0[4] = {}, ac1[4] = {};
#pragma unroll
        for (int kt = 0; kt < 2; ++kt) {
            const float* q0 = embed_i + (size_t)v0 * 64 + kt * 32 + quad * 8;
            const float* q1 = embed_i + (size_t)v1 * 64 + kt * 32 + quad * 8;
            s16x8 aq0 = mkfrag(*(const float4*)q0, *(const float4*)(q0 + 4));
            s16x8 aq1 = mkfrag(*(const float4*)q1, *(const float4*)(q1 + 4));
#pragma unroll
            for (int nt = 0; nt < 4; ++nt) {
                ac0[nt] = mfma16(aq0, bfr[kt * 4 + nt], ac0[nt]);
                ac1[nt] = mfma16(aq1, bfr[kt * 4 + nt], ac1[nt]);
            }
        }
#pragma unroll
        for (int nt = 0; nt < 4; ++nt) {
            int c = nt * 16 + m;
#pragma unroll
            for (int r4 = 0; r4 < 4; ++r4) {
                cq[(base + quad * 4 + r4) * 64 + c]      = ac0[nt][r4];
                cq[(base + 16 + quad * 4 + r4) * 64 + c] = ac1[nt][r4];
            }
        }
        return;
    }
    int i = blockIdx.x * 256 + threadIdx.x;
    if (i >= WT_TOTAL + 64) return;
    if (i >= WT_TOTAL) {                       // bias1'[n] = ab1[n] + sum_t gb3[t]*a1[t][n]
        int n = i - WT_TOTAL;
        float s0 = ab1[n], s1 = 0.f, s2 = 0.f, s3 = 0.f;
#pragma unroll
        for (int t = 0; t < 64; t += 4) {
            s0 = fmaf(gb3[t],     a1[t * 64 + n],       s0);
            s1 = fmaf(gb3[t + 1], a1[(t + 1) * 64 + n], s1);
            s2 = fmaf(gb3[t + 2], a1[(t + 2) * 64 + n], s2);
            s3 = fmaf(gb3[t + 3], a1[(t + 3) * 64 + n], s3);
        }
        bias1p[n] = (s0 + s1) + (s2 + s3);
        return;
    }
    float val;
    if (i < OFF_R1T) {
        int off, kind;   // 0=w1,1=w2,2=w3,3=wca,4=a2
        if      (i < OFF_W2F) { off = OFF_W1F; kind = 0; }
        else if (i < OFF_W3F) { off = OFF_W2F; kind = 1; }
        else if (i < OFF_WCF) { off = OFF_W3F; kind = 2; }
        else if (i < OFF_A2F) { off = OFF_WCF; kind = 3; }
        else                  { off = OFF_A2F; kind = 4; }
        int local = i - off;
        int f = local >> 9, lane = (local >> 3) & 63, j = local & 7;
        int kt = f >> 2, nt = f & 3, quad = lane >> 4, m = lane & 15;
        int k = kt * 32 + quad * 8 + j;
        int n = nt * 16 + m;
        if (kind == 0)      val = w1[k * 64 + n];
        else if (kind == 1) val = w2[k * 64 + n];
        else if (kind == 2) val = w3[k * 64 + n];
        else if (kind == 4) val = a2[k * 64 + n];
        else {                                  // wca[k][n] = (W3 @ A1_top)[k][n]
            float s0 = 0.f, s1 = 0.f, s2 = 0.f, s3 = 0.f;
#pragma unroll
            for (int t = 0; t < 64; t += 4) {
                float4 w = *(const float4*)(w3 + k * 64 + t);
                s0 = fmaf(w.x, a1[t * 64 + n],       s0);
                s1 = fmaf(w.y, a1[(t + 1) * 64 + n], s1);
                s2 = fmaf(w.z, a1[(t + 2) * 64 + n], s2);
                s3 = fmaf(w.w, a1[(t + 3) * 64 + n], s3);
            }
            val = (s0 + s1) + (s2 + s3);
        }
    }
    else if (i < OFF_R2T) { int li = i - OFF_R1T; int n = li >> 7, k = li & 127; val = r1[k * 64 + n]; }
    else                  { int li = i - OFF_R2T; int n = li >> 6, k = li & 63;  val = r2[k * 64 + n]; }
    wt[i] = (bf16)val;
}

// ---------------- fused: ONE ITEM PER WAVE, 64-thread blocks, ZERO barriers ----------------
// Each wave owns all 50 neighbors of one item as 4 A-tiles (rows t*16+quad*4+r4, clamped/masked
// past L). Softmax is fully in-wave (m-reduce shfl + quad shfl), no cross-wave merge, no idle
// waves in the tail. B-frags read once per item (global, L1/L2-hot). H (9.2 KB) is reused
// h1 -> h2 -> att1h, then overlaid as float zsh/qsh for the combine tail (lockstep-safe).
template<bool BF16E>
__global__ void __launch_bounds__(64, 3)
dense_fused(const int* __restrict__ nodes_v, const int* __restrict__ neigh_u,
            const int* __restrict__ neigh_r,
            const float* __restrict__ embed_u, const float* __restrict__ embed_i,
            const float* __restrict__ embed_r,
            const float* __restrict__ gv_b1, const float* __restrict__ gv_b2,
            const float* __restrict__ gv_b3,
            const float* __restrict__ att_b2, const float* __restrict__ att_w3,
            const float* __restrict__ wr1_b, const float* __restrict__ wr2_b,
            const bf16* __restrict__ wt, const bf16* __restrict__ eu16,
            const bf16* __restrict__ er16, const float* __restrict__ cq,
            const float* __restrict__ bias1p, float* __restrict__ out)
{
    __shared__ __align__(16) bf16 H[64 * SH];   // 9.2 KB: one item's 64 rows

    const int lane = threadIdx.x;               // block == wave
    const int m = lane & 15, quad = lane >> 4;
    const int b = blockIdx.x;

    // neighbor indices for this lane's 4 A-frag rows (clamped; pad rows masked at softmax)
    int un[4], vn[4];
#pragma unroll
    for (int t = 0; t < 4; ++t) {
        int l = min(t * 16 + m, L_ - 1);
        un[t] = neigh_u[b * L_ + l];
        vn[t] = neigh_r[b * L_ + l];
    }

    // att1 per-item bias, per-lane; L1/L2-hot
    float cs4[4];
#pragma unroll
    for (int nt = 0; nt < 4; ++nt) {
        int c = nt * 16 + m;
        cs4[nt] = cq[b * 64 + c] + bias1p[c];
    }

    // ---- gv1: h1 = relu([pt|er] @ W1 + b1) -> H ----
    {
        f32x4 ac[4][4] = {};   // [tile][nt]
#pragma unroll
        for (int kt = 0; kt < 4; ++kt) {
            s16x8 bfr[4];
#pragma unroll
            for (int nt = 0; nt < 4; ++nt)
                bfr[nt] = *(const s16x8*)(wt + OFF_W1F + (kt * 4 + nt) * 512 + lane * 8);
#pragma unroll
            for (int t = 0; t < 4; ++t) {
                s16x8 a;
                if constexpr (BF16E) {
                    const bf16* src = (kt < 2 ? eu16 + (size_t)un[t] * 64
                                              : er16 + (size_t)vn[t] * 64)
                                      + (kt & 1) * 32 + quad * 8;
                    a = ntload16(src);
                } else {
                    const float* src = (kt < 2 ? embed_u + (size_t)un[t] * 64
                                               : embed_r + (size_t)vn[t] * 64)
                                       + (kt & 1) * 32 + quad * 8;
                    a = mkfrag(*(const float4*)src, *(const float4*)(src + 4));
                }
#pragma unroll
                for (int nt = 0; nt < 4; ++nt)
                    ac[t][nt] = mfma16(a, bfr[nt], ac[t][nt]);
            }
        }
#pragma unroll
        for (int nt = 0; nt < 4; ++nt) {
            int c = nt * 16 + m;
            float bv = gv_b1[c];
#pragma unroll
            for (int t = 0; t < 4; ++t)
#pragma unroll
                for (int r4 = 0; r4 < 4; ++r4)
                    H[(t * 16 + quad * 4 + r4) * SH + c] = (bf16)fmaxf(ac[t][nt][r4] + bv, 0.f);
        }
    }

    // ---- gv2: h1 -> h2 (in-place, same-wave WAR safe) ----
    {
        f32x4 ac[4][4] = {};
#pragma unroll
        for (int kt = 0; kt < 2; ++kt) {
            s16x8 bfr[4];
#pragma unroll
            for (int nt = 0; nt < 4; ++nt)
                bfr[nt] = *(const s16x8*)(wt + OFF_W2F + (kt * 4 + nt) * 512 + lane * 8);
#pragma unroll
            for (int t = 0; t < 4; ++t) {
                s16x8 a = *(const s16x8*)(H + (t * 16 + m) * SH + kt * 32 + quad * 8);
#pragma unroll
                for (int nt = 0; nt < 4; ++nt)
                    ac[t][nt] = mfma16(a, bfr[nt], ac[t][nt]);
            }
        }
#pragma unroll
        for (int nt = 0; nt < 4; ++nt) {
            int c = nt * 16 + m;
            float bv = gv_b2[c];
#pragma unroll
            for (int t = 0; t < 4; ++t)
#pragma unroll
                for (int r4 = 0; r4 < 4; ++r4)
                    H[(t * 16 + quad * 4 + r4) * SH + c] = (bf16)fmaxf(ac[t][nt][r4] + bv, 0.f);
        }
    }

    // ---- fused gv3 + att1': consume h2; fjt stays in regs (aF), att1h -> H ----
    f32x4 aF[4][4] = {};
    {
        f32x4 aA[4][4] = {};
#pragma unroll
        for (int kt = 0; kt < 2; ++kt) {
            s16x8 bF[4], bA[4];
#pragma unroll
            for (int nt = 0; nt < 4; ++nt) {
                bF[nt] = *(const s16x8*)(wt + OFF_W3F + (kt * 4 + nt) * 512 + lane * 8);
                bA[nt] = *(const s16x8*)(wt + OFF_WCF + (kt * 4 + nt) * 512 + lane * 8);
            }
#pragma unroll
            for (int t = 0; t < 4; ++t) {
                s16x8 a = *(const s16x8*)(H + (t * 16 + m) * SH + kt * 32 + quad * 8);
#pragma unroll
                for (int nt = 0; nt < 4; ++nt) {
                    aF[t][nt] = mfma16(a, bF[nt], aF[t][nt]);
                    aA[t][nt] = mfma16(a, bA[nt], aA[t][nt]);
                }
            }
        }
        // write only att1h; aF kept in regs (gv_b3 folded into zj via sum(mu)==1)
#pragma unroll
        for (int nt = 0; nt < 4; ++nt) {
            int c = nt * 16 + m;
#pragma unroll
            for (int t = 0; t < 4; ++t)
#pragma unroll
                for (int r4 = 0; r4 < 4; ++r4)
                    H[(t * 16 + quad * 4 + r4) * SH + c] = (bf16)fmaxf(aA[t][nt][r4] + cs4[nt], 0.f);
        }
    }

    // ---- att2 + relu + dot(att_w3) + m-reduce -> per-row scores (m-uniform per quad) ----
    float sc[4][4];   // [tile][r4]
    {
        f32x4 ac[4][4] = {};
#pragma unroll
        for (int kt = 0; kt < 2; ++kt) {
            s16x8 bfr[4];
#pragma unroll
            for (int nt = 0; nt < 4; ++nt)
                bfr[nt] = *(const s16x8*)(wt + OFF_A2F + (kt * 4 + nt) * 512 + lane * 8);
#pragma unroll
            for (int t = 0; t < 4; ++t) {
                s16x8 a = *(const s16x8*)(H + (t * 16 + m) * SH + kt * 32 + quad * 8);
#pragma unroll
                for (int nt = 0; nt < 4; ++nt)
                    ac[t][nt] = mfma16(a, bfr[nt], ac[t][nt]);
            }
        }
#pragma unroll
        for (int t = 0; t < 4; ++t)
#pragma unroll
            for (int r4 = 0; r4 < 4; ++r4) sc[t][r4] = 0.f;
#pragma unroll
        for (int nt = 0; nt < 4; ++nt) {
            int c = nt * 16 + m;
            float b2v = att_b2[c], w3v = att_w3[c];
#pragma unroll
            for (int t = 0; t < 4; ++t)
#pragma unroll
                for (int r4 = 0; r4 < 4; ++r4)
                    sc[t][r4] += fmaxf(ac[t][nt][r4] + b2v, 0.f) * w3v;
        }
#pragma unroll
        for (int mask = 1; mask < 16; mask <<= 1)
#pragma unroll
            for (int t = 0; t < 4; ++t)
#pragma unroll
                for (int r4 = 0; r4 < 4; ++r4)
                    sc[t][r4] += __shfl_xor(sc[t][r4], mask);
    }

    // ---- in-wave softmax over the 50 real rows + e-weighted fjt sum ----
    float z[4], ssum;
    {
        float mloc = -1e30f;
#pragma unroll
        for (int t = 0; t < 4; ++t)
#pragma unroll
            for (int r4 = 0; r4 < 4; ++r4)
                if (t * 16 + quad * 4 + r4 < L_) mloc = fmaxf(mloc, sc[t][r4]);
        mloc = fmaxf(mloc, __shfl_xor(mloc, 16));
        mloc = fmaxf(mloc, __shfl_xor(mloc, 32));

        float e[4][4];
        ssum = 0.f;
#pragma unroll
        for (int t = 0; t < 4; ++t)
#pragma unroll
            for (int r4 = 0; r4 < 4; ++r4) {
                e[t][r4] = (t * 16 + quad * 4 + r4 < L_) ? __expf(sc[t][r4] - mloc) : 0.f;
                ssum += e[t][r4];
            }
        ssum += __shfl_xor(ssum, 16);
        ssum += __shfl_xor(ssum, 32);

#pragma unroll
        for (int nt = 0; nt < 4; ++nt) z[nt] = 0.f;
#pragma unroll
        for (int t = 0; t < 4; ++t)
#pragma unroll
            for (int r4 = 0; r4 < 4; ++r4)
#pragma unroll
                for (int nt = 0; nt < 4; ++nt)
                    z[nt] += aF[t][nt][r4] * e[t][r4];
#pragma unroll
        for (int nt = 0; nt < 4; ++nt) {
            z[nt] += __shfl_xor(z[nt], 16);
            z[nt] += __shfl_xor(z[nt], 32);
        }
    }

    // ---- tail (all in-wave): zj -> combine MLP -> out. Overlay H as float share bufs. ----
    {
        float* zsh = (float*)H;          // H is dead; lockstep wave => in-order LDS reuse safe
        float* qsh = zsh + 64;
#pragma unroll
        for (int nt = 0; nt < 4; ++nt) {
            int c = nt * 16 + m;
            zsh[c] = z[nt] / ssum + gv_b3[c];
        }
        const int d = lane;
        qsh[d] = embed_i[(size_t)nodes_v[b] * 64 + d];

        // z2 = relu([zj|q] @ wr1 + b1)   (2 accumulators to shorten the fmaf chain)
        float p0 = wr1_b[d], p1 = 0.f;
        const bf16* r1 = wt + OFF_R1T + d * 128;
#pragma unroll
        for (int k8 = 0; k8 < 8; ++k8) {
            b16x8 wv = *(const b16x8*)(r1 + k8 * 8);
#pragma unroll
            for (int j = 0; j < 8; j += 2) {
                p0 = fmaf((float)wv[j],     zsh[k8 * 8 + j],     p0);
                p1 = fmaf((float)wv[j + 1], zsh[k8 * 8 + j + 1], p1);
            }
        }
#pragma unroll
        for (int k8 = 0; k8 < 8; ++k8) {
            b16x8 wv = *(const b16x8*)(r1 + 64 + k8 * 8);
#pragma unroll
            for (int j = 0; j < 8; j += 2) {
                p0 = fmaf((float)wv[j],     qsh[k8 * 8 + j],     p0);
                p1 = fmaf((float)wv[j + 1], qsh[k8 * 8 + j + 1], p1);
            }
        }
        zsh[d] = fmaxf(p0 + p1, 0.f);   // all zsh/qsh reads above retire first (lockstep)

        // out = relu(z2 @ wr2 + b2)
        float q0 = wr2_b[d], q1 = 0.f;
        const bf16* r2 = wt + OFF_R2T + d * 64;
#pragma unroll
        for (int k8 = 0; k8 < 8; ++k8) {
            b16x8 wv = *(const b16x8*)(r2 + k8 * 8);
#pragma unroll
            for (int j = 0; j < 8; j += 2) {
                q0 = fmaf((float)wv[j],     zsh[k8 * 8 + j],     q0);
                q1 = fmaf((float)wv[j + 1], zsh[k8 * 8 + j + 1], q1);
            }
        }
        out[(size_t)b * 64 + d] = fmaxf(q0 + q1, 0.f);
    }
}

extern "C" void kernel_launch(void* const* d_in, const int* in_sizes, int n_in,
                              void* d_out, int out_size, void* d_ws, size_t ws_size,
                              hipStream_t stream)
{
    const int* nodes_v = (const int*)d_in[0];
    const int* neigh_u = (const int*)d_in[1];
    const int* neigh_r = (const int*)d_in[2];
    const float* embed_u = (const float*)d_in[3];
    const float* embed_i = (const float*)d_in[4];
    const float* embed_r = (const float*)d_in[5];
    const float* gv_w1  = (const float*)d_in[6];  const float* gv_b1 = (const float*)d_in[7];
    const float* gv_w2  = (const float*)d_in[8];  const float* gv_b2 = (const float*)d_in[9];
    const float* gv_w3  = (const float*)d_in[10]; const float* gv_b3 = (const float*)d_in[11];
    const float* att_w1 = (const float*)d_in[12]; const float* att_b1 = (const float*)d_in[13];
    const float* att_w2 = (const float*)d_in[14]; const float* att_b2 = (const float*)d_in[15];
    const float* att_w3 = (const float*)d_in[16]; const float* att_b3 = (const float*)d_in[17];
    const float* wr1_w  = (const float*)d_in[18]; const float* wr1_b = (const float*)d_in[19];
    const float* wr2_w  = (const float*)d_in[20]; const float* wr2_b = (const float*)d_in[21];
    (void)att_b3;  // softmax shift-invariance

    bf16*  wt     = (bf16*)d_ws;
    float* bias1p = (float*)((char*)d_ws + BIAS1P_BYTE);
    float* cq     = (float*)((char*)d_ws + CQ_BYTE);
    bf16*  eu16   = (bf16*)((char*)d_ws + EU16_BYTE);
    bf16*  er16   = (bf16*)((char*)d_ws + ER16_BYTE);

    const bool big = ws_size >= (size_t)WS_NEED;
    const int prep_grid = PREP_W_BLOCKS + CQ_BLOCKS + (big ? CONV_BLOCKS : 0);

    prep_all<<<prep_grid, 256, 0, stream>>>(
        gv_w1, gv_w2, gv_w3, att_w1, att_w2, wr1_w, wr2_w, gv_b3, att_b1,
        nodes_v, embed_i, embed_u, embed_r, wt, bias1p, cq, eu16, er16);

    if (big) {
        dense_fused<true><<<B_, 64, 0, stream>>>(nodes_v, neigh_u, neigh_r,
                                                 embed_u, embed_i, embed_r,
                                                 gv_b1, gv_b2, gv_b3, att_b2, att_w3,
                                                 wr1_b, wr2_b, wt, eu16, er16,
                                                 cq, bias1p, (float*)d_out);
    } else {
        dense_fused<false><<<B_, 64, 0, stream>>>(nodes_v, neigh_u, neigh_r,
                                                  embed_u, embed_i, embed_r,
                                                  gv_b1, gv_b2, gv_b3, att_b2, att_w3,
                                                  wr1_b, wr2_b, wt, eu16, er16,
                                                  cq, bias1p, (float*)d_out);
    }
}

// Round 6
// 168.549 us; speedup vs baseline: 1.0525x; 1.0525x over previous
//
#include <hip/hip_runtime.h>

typedef __bf16 bf16;
typedef short s16x8 __attribute__((ext_vector_type(8)));   // 8 bf16 bit-patterns for MFMA frags
typedef __bf16 b16x8 __attribute__((ext_vector_type(8)));  // 8 bf16 for scalar convert paths
typedef float f32x4 __attribute__((ext_vector_type(4)));

#define B_   4096
#define L_   50
#define SH   72               // H row stride (bf16): 64 + 8 pad (2-way bank alias, free)

// ws layout, bf16 elems. Frag-major matrices: frag f = kt*4+nt is a contiguous
// 512-elem (1 KB) block; elem = f*512 + lane*8 + j -> W[k=kt*32+(lane>>4)*8+j][n=nt*16+(lane&15)].
#define OFF_W1F  0            // gv_w1  frag-major, K=128 (16 frags) -- fallback path only
#define OFF_W2F  8192         // gv_w2  frag-major, K=64 (8 frags)
#define OFF_W3F  12288        // gv_w3  frag-major
#define OFF_WCF  16384        // (gv_w3 @ att_w1_top) frag-major
#define OFF_A2F  20480        // att_w2 frag-major
#define OFF_R1T  24576        // [64][128] wr1^T row-major (combine tail per-lane dots)
#define OFF_R2T  32768        // [64][64]  wr2^T row-major
#define WT_TOTAL 36864
#define HERR_N   320          // 5 x 64 f32: er@W1_bot + b1 (bf16-rounded inputs, f32 accum)
// byte offsets in ws:
#define BIAS1P_BYTE 73728     // float[64]         att_b1 + gv_b3 @ att_w1_top
#define CQ_BYTE     73984     // float[4096][64]   q_b @ A1_bot  (bias1p added in dense)
#define HERR_BYTE   1122560   // float[5][64]      er-part of layer1 (+b1)
#define H1U_BYTE    1123840   // float[100000][64] pt@W1_top precomputed (layer-1 user part)
#define WS_NEED     26723840

#define PREP_W_BLOCKS 146     // ceil((WT_TOTAL+64+HERR_N)/256)
#define CQ_BLOCKS     32      // 4096 items / (4 waves x 32 items) -- MFMA cq
#define H1U_BLOCKS    782     // ceil(100000/32 rows / 4 waves)    -- MFMA h1u

__device__ __forceinline__ unsigned short f2b(float f) {
    __bf16 h = (__bf16)f;
    return __builtin_bit_cast(unsigned short, h);
}
__device__ __forceinline__ float bround(float f) {       // RNE bf16 round-trip
    return (float)(__bf16)f;
}
__device__ __forceinline__ unsigned pack2(float a, float b) {
    return (unsigned)f2b(a) | ((unsigned)f2b(b) << 16);
}
__device__ __forceinline__ s16x8 mkfrag(float4 a, float4 b) {
    union { s16x8 v; unsigned u[4]; } r;
    r.u[0] = pack2(a.x, a.y); r.u[1] = pack2(a.z, a.w);
    r.u[2] = pack2(b.x, b.y); r.u[3] = pack2(b.z, b.w);
    return r.v;
}
__device__ __forceinline__ f32x4 mfma16(s16x8 a, s16x8 b, f32x4 c) {
    return __builtin_amdgcn_mfma_f32_16x16x32_bf16(a, b, c, 0, 0, 0);
}

// -------- prep (single launch): frag-major weights + bias1' + herr + MFMA cq + MFMA h1u --------
extern "C" __global__ void prep_all(const float* __restrict__ w1, const float* __restrict__ w2,
                                    const float* __restrict__ w3, const float* __restrict__ a1,
                                    const float* __restrict__ a2, const float* __restrict__ r1,
                                    const float* __restrict__ r2, const float* __restrict__ gb3,
                                    const float* __restrict__ ab1, const float* __restrict__ gb1,
                                    const int* __restrict__ nodes_v, const float* __restrict__ embed_i,
                                    const float* __restrict__ embed_u, const float* __restrict__ embed_r,
                                    bf16* __restrict__ wt, float* __restrict__ bias1p,
                                    float* __restrict__ cq, float* __restrict__ herr,
                                    float* __restrict__ h1u)
{
    if (blockIdx.x >= PREP_W_BLOCKS + CQ_BLOCKS) {
        // h1u[i][n] = bf16(embed_u[i]) @ bf16(W1_top) via MFMA: wave = 32 rows, K=64, N=64.
        int wv   = (blockIdx.x - PREP_W_BLOCKS - CQ_BLOCKS) * 4 + (threadIdx.x >> 6);
        int base = wv * 32;
        if (base >= 100000) return;
        int lane = threadIdx.x & 63, m = lane & 15, quad = lane >> 4;
        int i0 = base + m, i1 = base + 16 + m;

        s16x8 bfr[8];
#pragma unroll
        for (int kt = 0; kt < 2; ++kt)
#pragma unroll
            for (int nt = 0; nt < 4; ++nt) {
                const float* src = w1 + (kt * 32 + quad * 8) * 64 + nt * 16 + m;
                union { s16x8 v; unsigned u[4]; } fr;
#pragma unroll
                for (int jj = 0; jj < 4; ++jj)
                    fr.u[jj] = pack2(src[(2 * jj) * 64], src[(2 * jj + 1) * 64]);
                bfr[kt * 4 + nt] = fr.v;
            }

        f32x4 ac0[4] = {}, ac1[4] = {};
#pragma unroll
        for (int kt = 0; kt < 2; ++kt) {
            const float* q0 = embed_u + (size_t)i0 * 64 + kt * 32 + quad * 8;
            const float* q1 = embed_u + (size_t)i1 * 64 + kt * 32 + quad * 8;
            s16x8 aq0 = mkfrag(*(const float4*)q0, *(const float4*)(q0 + 4));
            s16x8 aq1 = mkfrag(*(const float4*)q1, *(const float4*)(q1 + 4));
#pragma unroll
            for (int nt = 0; nt < 4; ++nt) {
                ac0[nt] = mfma16(aq0, bfr[kt * 4 + nt], ac0[nt]);
                ac1[nt] = mfma16(aq1, bfr[kt * 4 + nt], ac1[nt]);
            }
        }
#pragma unroll
        for (int nt = 0; nt < 4; ++nt) {
            int c = nt * 16 + m;
#pragma unroll
            for (int r4 = 0; r4 < 4; ++r4) {
                h1u[(size_t)(base + quad * 4 + r4) * 64 + c]      = ac0[nt][r4];
                h1u[(size_t)(base + 16 + quad * 4 + r4) * 64 + c] = ac1[nt][r4];
            }
        }
        return;
    }
    if (blockIdx.x >= PREP_W_BLOCKS) {
        // cq[i][n] = q_i @ A1_bot via MFMA: wave = 32 items (2 A-tiles), K=64, N=64.
        int wv   = (blockIdx.x - PREP_W_BLOCKS) * 4 + (threadIdx.x >> 6);   // 0..127
        int lane = threadIdx.x & 63, m = lane & 15, quad = lane >> 4;
        int base = wv * 32;
        int i0 = base + m, i1 = base + 16 + m;
        int v0 = nodes_v[i0], v1 = nodes_v[i1];

        s16x8 bfr[8];
#pragma unroll
        for (int kt = 0; kt < 2; ++kt)
#pragma unroll
            for (int nt = 0; nt < 4; ++nt) {
                const float* src = a1 + (64 + kt * 32 + quad * 8) * 64 + nt * 16 + m;
                union { s16x8 v; unsigned u[4]; } fr;
#pragma unroll
                for (int jj = 0; jj < 4; ++jj)
                    fr.u[jj] = pack2(src[(2 * jj) * 64], src[(2 * jj + 1) * 64]);
                bfr[kt * 4 + nt] = fr.v;
            }

        f32x4 ac0[4] = {}, ac1[4] = {};
#pragma unroll
        for (int kt = 0; kt < 2; ++kt) {
            const float* q0 = embed_i + (size_t)v0 * 64 + kt * 32 + quad * 8;
            const float* q1 = embed_i + (size_t)v1 * 64 + kt * 32 + quad * 8;
            s16x8 aq0 = mkfrag(*(const float4*)q0, *(const float4*)(q0 + 4));
            s16x8 aq1 = mkfrag(*(const float4*)q1, *(const float4*)(q1 + 4));
#pragma unroll
            for (int nt = 0; nt < 4; ++nt) {
                ac0[nt] = mfma16(aq0, bfr[kt * 4 + nt], ac0[nt]);
                ac1[nt] = mfma16(aq1, bfr[kt * 4 + nt], ac1[nt]);
            }
        }
#pragma unroll
        for (int nt = 0; nt < 4; ++nt) {
            int c = nt * 16 + m;
#pragma unroll
            for (int r4 = 0; r4 < 4; ++r4) {
                cq[(base + quad * 4 + r4) * 64 + c]      = ac0[nt][r4];
                cq[(base + 16 + quad * 4 + r4) * 64 + c] = ac1[nt][r4];
            }
        }
        return;
    }
    int i = blockIdx.x * 256 + threadIdx.x;
    if (i >= WT_TOTAL + 64 + HERR_N) return;
    if (i >= WT_TOTAL + 64) {                  // herr[r][n] = b1[n] + sum_k bf(er[r][k])*bf(w1[64+k][n])
        int i2 = i - (WT_TOTAL + 64);
        int r = i2 >> 6, n = i2 & 63;
        float s0 = gb1[n], s1 = 0.f, s2 = 0.f, s3 = 0.f;
        const float* er = embed_r + r * 64;
#pragma unroll
        for (int k = 0; k < 64; k += 4) {
            s0 = fmaf(bround(er[k]),     bround(w1[(64 + k) * 64 + n]),     s0);
            s1 = fmaf(bround(er[k + 1]), bround(w1[(64 + k + 1) * 64 + n]), s1);
            s2 = fmaf(bround(er[k + 2]), bround(w1[(64 + k + 2) * 64 + n]), s2);
            s3 = fmaf(bround(er[k + 3]), bround(w1[(64 + k + 3) * 64 + n]), s3);
        }
        herr[i2] = (s0 + s1) + (s2 + s3);
        return;
    }
    if (i >= WT_TOTAL) {                       // bias1'[n] = ab1[n] + sum_t gb3[t]*a1[t][n]
        int n = i - WT_TOTAL;
        float s0 = ab1[n], s1 = 0.f, s2 = 0.f, s3 = 0.f;
#pragma unroll
        for (int t = 0; t < 64; t += 4) {
            s0 = fmaf(gb3[t],     a1[t * 64 + n],       s0);
            s1 = fmaf(gb3[t + 1], a1[(t + 1) * 64 + n], s1);
            s2 = fmaf(gb3[t + 2], a1[(t + 2) * 64 + n], s2);
            s3 = fmaf(gb3[t + 3], a1[(t + 3) * 64 + n], s3);
        }
        bias1p[n] = (s0 + s1) + (s2 + s3);
        return;
    }
    float val;
    if (i < OFF_R1T) {
        int off, kind;   // 0=w1,1=w2,2=w3,3=wca,4=a2
        if      (i < OFF_W2F) { off = OFF_W1F; kind = 0; }
        else if (i < OFF_W3F) { off = OFF_W2F; kind = 1; }
        else if (i < OFF_WCF) { off = OFF_W3F; kind = 2; }
        else if (i < OFF_A2F) { off = OFF_WCF; kind = 3; }
        else                  { off = OFF_A2F; kind = 4; }
        int local = i - off;
        int f = local >> 9, lane = (local >> 3) & 63, j = local & 7;
        int kt = f >> 2, nt = f & 3, quad = lane >> 4, m = lane & 15;
        int k = kt * 32 + quad * 8 + j;
        int n = nt * 16 + m;
        if (kind == 0)      val = w1[k * 64 + n];
        else if (kind == 1) val = w2[k * 64 + n];
        else if (kind == 2) val = w3[k * 64 + n];
        else if (kind == 4) val = a2[k * 64 + n];
        else {                                  // wca[k][n] = (W3 @ A1_top)[k][n]
            float s0 = 0.f, s1 = 0.f, s2 = 0.f, s3 = 0.f;
#pragma unroll
            for (int t = 0; t < 64; t += 4) {
                float4 w = *(const float4*)(w3 + k * 64 + t);
                s0 = fmaf(w.x, a1[t * 64 + n],       s0);
                s1 = fmaf(w.y, a1[(t + 1) * 64 + n], s1);
                s2 = fmaf(w.z, a1[(t + 2) * 64 + n], s2);
                s3 = fmaf(w.w, a1[(t + 3) * 64 + n], s3);
            }
            val = (s0 + s1) + (s2 + s3);
        }
    }
    else if (i < OFF_R2T) { int li = i - OFF_R1T; int n = li >> 7, k = li & 127; val = r1[k * 64 + n]; }
    else                  { int li = i - OFF_R2T; int n = li >> 6, k = li & 63;  val = r2[k * 64 + n]; }
    wt[i] = (bf16)val;
}

// ---------------- fused: 2 items x 64 rows/block, dual-tile waves, ONE barrier ----------------
// R2 structure (best measured) with LAYER-1 HOISTED TO PREP: gv1 becomes
// h1 = relu(h1u[u] + herr[r]) -- two f32 row-gathers + add + relu + one ds_write_b128 per
// 8 cols, deleting 16 MFMA + 8 embedding gathers + 32 scalar H stores + 32 cvts per wave and
// removing the gather->MFMA chain from the critical path. PRE=false keeps the old in-kernel
// gv1 (f32 embedding gathers + W1F MFMA) for small-ws fallback.
template<bool PRE>
__global__ void __launch_bounds__(256, 2)
dense_fused(const int* __restrict__ nodes_v, const int* __restrict__ neigh_u,
            const int* __restrict__ neigh_r,
            const float* __restrict__ embed_u, const float* __restrict__ embed_i,
            const float* __restrict__ embed_r,
            const float* __restrict__ gv_b1, const float* __restrict__ gv_b2,
            const float* __restrict__ gv_b3,
            const float* __restrict__ att_b2, const float* __restrict__ att_w3,
            const float* __restrict__ wr1_b, const float* __restrict__ wr2_b,
            const bf16* __restrict__ wt, const float* __restrict__ h1u,
            const float* __restrict__ herr, const float* __restrict__ cq,
            const float* __restrict__ bias1p, float* __restrict__ out)
{
    __shared__ __align__(16) bf16 H[128 * SH];      // 18.4 KB: h1 -> h2 -> att1h (same-wave reuse)
    __shared__ float zp[4 * 64];                    // per-wave e-weighted fjt partial S_w[64]
    __shared__ float swm[4 * 2];                    // per-wave {sum_e, max}
    __shared__ float qsh[2 * 64];                   // q per item (staged by tail wave)

    const int tid = threadIdx.x;
    const int lane = tid & 63, wave = tid >> 6;
    const int m = lane & 15, quad = lane >> 4;
    const int b0 = blockIdx.x * 2;
    const int rw0 = wave * 32;                      // wave's rows in [0,128)
    const int item_w = rw0 >> 6;                    // this wave's item (0/1)
    const int lbase = rw0 & 63;                     // neighbor offset within item (0/32)

    // neighbor indices for this lane's two A-frag rows (clamped; pad rows masked at softmax)
    const int bw = b0 + item_w;
    const int l0 = min(lbase + m, L_ - 1);
    const int l1 = min(lbase + 16 + m, L_ - 1);
    const int u0 = neigh_u[bw * L_ + l0], u1 = neigh_u[bw * L_ + l1];
    const int v0 = neigh_r[bw * L_ + l0], v1 = neigh_r[bw * L_ + l1];

    // att1 per-item bias, per-lane; hoisted early, L1/L2-hot
    float cs4[4];
#pragma unroll
    for (int nt = 0; nt < 4; ++nt) {
        int c = nt * 16 + m;
        cs4[nt] = cq[bw * 64 + c] + bias1p[c];
    }

    bf16* Hw = H + rw0 * SH;   // this wave's 32 rows
    bf16* H0 = Hw;             // tile 0
    bf16* H1 = Hw + 16 * SH;   // tile 1

    // ---- gv1: h1 = relu(h1u[u] + herr[r]) -> H  (layer-1 MFMA hoisted to prep) ----
    if constexpr (PRE) {
        const float* hu0 = h1u + (size_t)u0 * 64;
        const float* hu1 = h1u + (size_t)u1 * 64;
        const float* he0 = herr + v0 * 64;
        const float* he1 = herr + v1 * 64;
#pragma unroll
        for (int half = 0; half < 2; ++half) {
            const int cb = half * 32 + quad * 8;
            float4 x0 = *(const float4*)(hu0 + cb), x1 = *(const float4*)(hu0 + cb + 4);
            float4 y0 = *(const float4*)(he0 + cb), y1 = *(const float4*)(he0 + cb + 4);
            union { s16x8 v; unsigned u[4]; } ra;
            ra.u[0] = pack2(fmaxf(x0.x + y0.x, 0.f), fmaxf(x0.y + y0.y, 0.f));
            ra.u[1] = pack2(fmaxf(x0.z + y0.z, 0.f), fmaxf(x0.w + y0.w, 0.f));
            ra.u[2] = pack2(fmaxf(x1.x + y1.x, 0.f), fmaxf(x1.y + y1.y, 0.f));
            ra.u[3] = pack2(fmaxf(x1.z + y1.z, 0.f), fmaxf(x1.w + y1.w, 0.f));
            *(s16x8*)(H0 + m * SH + cb) = ra.v;

            float4 p0 = *(const float4*)(hu1 + cb), p1 = *(const float4*)(hu1 + cb + 4);
            float4 q0 = *(const float4*)(he1 + cb), q1 = *(const float4*)(he1 + cb + 4);
            union { s16x8 v; unsigned u[4]; } rb;
            rb.u[0] = pack2(fmaxf(p0.x + q0.x, 0.f), fmaxf(p0.y + q0.y, 0.f));
            rb.u[1] = pack2(fmaxf(p0.z + q0.z, 0.f), fmaxf(p0.w + q0.w, 0.f));
            rb.u[2] = pack2(fmaxf(p1.x + q1.x, 0.f), fmaxf(p1.y + q1.y, 0.f));
            rb.u[3] = pack2(fmaxf(p1.z + q1.z, 0.f), fmaxf(p1.w + q1.w, 0.f));
            *(s16x8*)(H1 + m * SH + cb) = rb.v;
        }
    } else {
        f32x4 ac0[4] = {}, ac1[4] = {};
        const float* b00 = embed_u + (size_t)u0 * 64;
        const float* b01 = embed_u + (size_t)u1 * 64;
        const float* b10 = embed_r + v0 * 64;
        const float* b11 = embed_r + v1 * 64;
#pragma unroll
        for (int kt = 0; kt < 4; ++kt) {
            const float* s0p = (kt < 2 ? b00 : b10) + (kt & 1) * 32 + quad * 8;
            const float* s1p = (kt < 2 ? b01 : b11) + (kt & 1) * 32 + quad * 8;
            s16x8 a0 = mkfrag(*(const float4*)s0p, *(const float4*)(s0p + 4));
            s16x8 a1 = mkfrag(*(const float4*)s1p, *(const float4*)(s1p + 4));
#pragma unroll
            for (int nt = 0; nt < 4; ++nt) {
                s16x8 bfr = *(const s16x8*)(wt + OFF_W1F + (kt * 4 + nt) * 512 + lane * 8);
                ac0[nt] = mfma16(a0, bfr, ac0[nt]);
                ac1[nt] = mfma16(a1, bfr, ac1[nt]);
            }
        }
#pragma unroll
        for (int nt = 0; nt < 4; ++nt) {
            int c = nt * 16 + m;
            float bv = gv_b1[c];
#pragma unroll
            for (int r4 = 0; r4 < 4; ++r4) {
                H0[(quad * 4 + r4) * SH + c] = (bf16)fmaxf(ac0[nt][r4] + bv, 0.f);
                H1[(quad * 4 + r4) * SH + c] = (bf16)fmaxf(ac1[nt][r4] + bv, 0.f);
            }
        }
    }

    // ---- gv2: h1 -> h2 (in-place, same-wave WAR safe) ----
    {
        f32x4 ac0[4] = {}, ac1[4] = {};
#pragma unroll
        for (int kt = 0; kt < 2; ++kt) {
            s16x8 a0 = *(const s16x8*)(H0 + m * SH + kt * 32 + quad * 8);
            s16x8 a1 = *(const s16x8*)(H1 + m * SH + kt * 32 + quad * 8);
#pragma unroll
            for (int nt = 0; nt < 4; ++nt) {
                s16x8 bfr = *(const s16x8*)(wt + OFF_W2F + (kt * 4 + nt) * 512 + lane * 8);
                ac0[nt] = mfma16(a0, bfr, ac0[nt]);
                ac1[nt] = mfma16(a1, bfr, ac1[nt]);
            }
        }
#pragma unroll
        for (int nt = 0; nt < 4; ++nt) {
            int c = nt * 16 + m;
            float bv = gv_b2[c];
#pragma unroll
            for (int r4 = 0; r4 < 4; ++r4) {
                H0[(quad * 4 + r4) * SH + c] = (bf16)fmaxf(ac0[nt][r4] + bv, 0.f);
                H1[(quad * 4 + r4) * SH + c] = (bf16)fmaxf(ac1[nt][r4] + bv, 0.f);
            }
        }
    }

    // ---- fused gv3 + att1': consume h2; fjt stays in regs (aF), att1h -> H ----
    f32x4 aF0[4] = {}, aF1[4] = {};
    {
        f32x4 aA0[4] = {}, aA1[4] = {};
#pragma unroll
        for (int kt = 0; kt < 2; ++kt) {
            s16x8 a0 = *(const s16x8*)(H0 + m * SH + kt * 32 + quad * 8);
            s16x8 a1 = *(const s16x8*)(H1 + m * SH + kt * 32 + quad * 8);
#pragma unroll
            for (int nt = 0; nt < 4; ++nt) {
                s16x8 bF = *(const s16x8*)(wt + OFF_W3F + (kt * 4 + nt) * 512 + lane * 8);
                s16x8 bA = *(const s16x8*)(wt + OFF_WCF + (kt * 4 + nt) * 512 + lane * 8);
                aF0[nt] = mfma16(a0, bF, aF0[nt]);
                aF1[nt] = mfma16(a1, bF, aF1[nt]);
                aA0[nt] = mfma16(a0, bA, aA0[nt]);
                aA1[nt] = mfma16(a1, bA, aA1[nt]);
            }
        }
        // write only att1h; aF kept in regs (gv_b3 folded into zj via sum(mu)==1)
#pragma unroll
        for (int nt = 0; nt < 4; ++nt) {
            int c = nt * 16 + m;
#pragma unroll
            for (int r4 = 0; r4 < 4; ++r4) {
                H0[(quad * 4 + r4) * SH + c] = (bf16)fmaxf(aA0[nt][r4] + cs4[nt], 0.f);
                H1[(quad * 4 + r4) * SH + c] = (bf16)fmaxf(aA1[nt][r4] + cs4[nt], 0.f);
            }
        }
    }

    // ---- att2 + relu + dot(att_w3) + m-reduce -> per-row scores in regs ----
    float s0[4], s1[4];
    {
        f32x4 ac0[4] = {}, ac1[4] = {};
#pragma unroll
        for (int kt = 0; kt < 2; ++kt) {
            s16x8 a0 = *(const s16x8*)(H0 + m * SH + kt * 32 + quad * 8);
            s16x8 a1 = *(const s16x8*)(H1 + m * SH + kt * 32 + quad * 8);
#pragma unroll
            for (int nt = 0; nt < 4; ++nt) {
                s16x8 bfr = *(const s16x8*)(wt + OFF_A2F + (kt * 4 + nt) * 512 + lane * 8);
                ac0[nt] = mfma16(a0, bfr, ac0[nt]);
                ac1[nt] = mfma16(a1, bfr, ac1[nt]);
            }
        }
#pragma unroll
        for (int r4 = 0; r4 < 4; ++r4) { s0[r4] = 0.f; s1[r4] = 0.f; }
#pragma unroll
        for (int nt = 0; nt < 4; ++nt) {
            int c = nt * 16 + m;
            float b2v = att_b2[c], w3v = att_w3[c];
#pragma unroll
            for (int r4 = 0; r4 < 4; ++r4) {
                s0[r4] += fmaxf(ac0[nt][r4] + b2v, 0.f) * w3v;
                s1[r4] += fmaxf(ac1[nt][r4] + b2v, 0.f) * w3v;
            }
        }
        // reduce across the 16 m-lanes (masks 1,2,4,8): scores become m-uniform per quad
#pragma unroll
        for (int mask = 1; mask < 16; mask <<= 1)
#pragma unroll
            for (int r4 = 0; r4 < 4; ++r4) {
                s0[r4] += __shfl_xor(s0[r4], mask);
                s1[r4] += __shfl_xor(s1[r4], mask);
            }
    }

    // ---- per-wave ONLINE-softmax partial over this wave's 32 rows (no cross-wave data) ----
    {
        // rows: tile0 = lbase + quad*4 + r4 ; tile1 = +16. Mask pad rows (>= L_).
        const int r0b = lbase + quad * 4;
        float mloc = -1e30f;
#pragma unroll
        for (int r4 = 0; r4 < 4; ++r4) {
            if (r0b + r4 < L_)      mloc = fmaxf(mloc, s0[r4]);
            if (r0b + 16 + r4 < L_) mloc = fmaxf(mloc, s1[r4]);
        }
        mloc = fmaxf(mloc, __shfl_xor(mloc, 16));
        mloc = fmaxf(mloc, __shfl_xor(mloc, 32));   // wave-local max (m-uniform already)

        float e0[4], e1[4], ssum = 0.f;
#pragma unroll
        for (int r4 = 0; r4 < 4; ++r4) {
            e0[r4] = (r0b + r4 < L_)      ? __expf(s0[r4] - mloc) : 0.f;
            e1[r4] = (r0b + 16 + r4 < L_) ? __expf(s1[r4] - mloc) : 0.f;
            ssum += e0[r4] + e1[r4];
        }
        ssum += __shfl_xor(ssum, 16);
        ssum += __shfl_xor(ssum, 32);

        float z[4] = {0.f, 0.f, 0.f, 0.f};
#pragma unroll
        for (int r4 = 0; r4 < 4; ++r4)
#pragma unroll
            for (int nt = 0; nt < 4; ++nt)
                z[nt] += aF0[nt][r4] * e0[r4] + aF1[nt][r4] * e1[r4];
#pragma unroll
        for (int nt = 0; nt < 4; ++nt) {
            z[nt] += __shfl_xor(z[nt], 16);
            z[nt] += __shfl_xor(z[nt], 32);
        }
        if (quad == 0) {
#pragma unroll
            for (int nt = 0; nt < 4; ++nt) zp[wave * 64 + nt * 16 + m] = z[nt];
        }
        if (lane == 0) { swm[wave * 2] = ssum; swm[wave * 2 + 1] = mloc; }
    }
    __syncthreads();   // the ONLY barrier

    // ---- tail: wave 0 -> item 0, wave 2 -> item 1 (online-softmax merge + combine) ----
    if ((wave & 1) == 0) {
        const int item = wave >> 1;
        const int d = lane;
        float ma = swm[wave * 2 + 1],      mb = swm[(wave + 1) * 2 + 1];
        float sa = swm[wave * 2],          sb = swm[(wave + 1) * 2];
        float M  = fmaxf(ma, mb);
        float fa = __expf(ma - M), fb = __expf(mb - M);
        float zj = (fa * zp[wave * 64 + d] + fb * zp[(wave + 1) * 64 + d])
                 / (fa * sa + fb * sb) + gv_b3[d];

        // share zj and q via LDS (same-wave in-order; zp[wave] slot is dead after the read above)
        float* zsh = zp + wave * 64;
        zsh[d] = zj;
        qsh[item * 64 + d] = embed_i[nodes_v[b0 + item] * 64 + d];

        // z2 = relu([zj|q] @ wr1 + b1)
        float accz = wr1_b[d];
        const bf16* r1 = wt + OFF_R1T + d * 128;
#pragma unroll
        for (int k8 = 0; k8 < 8; ++k8) {
            b16x8 wv = *(const b16x8*)(r1 + k8 * 8);
#pragma unroll
            for (int j = 0; j < 8; ++j) accz = fmaf((float)wv[j], zsh[k8 * 8 + j], accz);
        }
#pragma unroll
        for (int k8 = 0; k8 < 8; ++k8) {
            b16x8 wv = *(const b16x8*)(r1 + 64 + k8 * 8);
#pragma unroll
            for (int j = 0; j < 8; ++j) accz = fmaf((float)wv[j], qsh[item * 64 + k8 * 8 + j], accz);
        }
        zsh[d] = fmaxf(accz, 0.f);   // reuse as z2-share (same-wave in-order)

        // out = relu(z2 @ wr2 + b2)
        float acco = wr2_b[d];
        const bf16* r2 = wt + OFF_R2T + d * 64;
#pragma unroll
        for (int k8 = 0; k8 < 8; ++k8) {
            b16x8 wv = *(const b16x8*)(r2 + k8 * 8);
#pragma unroll
            for (int j = 0; j < 8; ++j) acco = fmaf((float)wv[j], zsh[k8 * 8 + j], acco);
        }
        out[(b0 + item) * 64 + d] = fmaxf(acco, 0.f);
    }
}

extern "C" void kernel_launch(void* const* d_in, const int* in_sizes, int n_in,
                              void* d_out, int out_size, void* d_ws, size_t ws_size,
                              hipStream_t stream)
{
    const int* nodes_v = (const int*)d_in[0];
    const int* neigh_u = (const int*)d_in[1];
    const int* neigh_r = (const int*)d_in[2];
    const float* embed_u = (const float*)d_in[3];
    const float* embed_i = (const float*)d_in[4];
    const float* embed_r = (const float*)d_in[5];
    const float* gv_w1  = (const float*)d_in[6];  const float* gv_b1 = (const float*)d_in[7];
    const float* gv_w2  = (const float*)d_in[8];  const float* gv_b2 = (const float*)d_in[9];
    const float* gv_w3  = (const float*)d_in[10]; const float* gv_b3 = (const float*)d_in[11];
    const float* att_w1 = (const float*)d_in[12]; const float* att_b1 = (const float*)d_in[13];
    const float* att_w2 = (const float*)d_in[14]; const float* att_b2 = (const float*)d_in[15];
    const float* att_w3 = (const float*)d_in[16]; const float* att_b3 = (const float*)d_in[17];
    const float* wr1_w  = (const float*)d_in[18]; const float* wr1_b = (const float*)d_in[19];
    const float* wr2_w  = (const float*)d_in[20]; const float* wr2_b = (const float*)d_in[21];
    (void)att_b3;  // softmax shift-invariance

    bf16*  wt     = (bf16*)d_ws;
    float* bias1p = (float*)((char*)d_ws + BIAS1P_BYTE);
    float* cq     = (float*)((char*)d_ws + CQ_BYTE);
    float* herr   = (float*)((char*)d_ws + HERR_BYTE);
    float* h1u    = (float*)((char*)d_ws + H1U_BYTE);

    const bool big = ws_size >= (size_t)WS_NEED;
    const int prep_grid = PREP_W_BLOCKS + CQ_BLOCKS + (big ? H1U_BLOCKS : 0);

    prep_all<<<prep_grid, 256, 0, stream>>>(
        gv_w1, gv_w2, gv_w3, att_w1, att_w2, wr1_w, wr2_w, gv_b3, att_b1, gv_b1,
        nodes_v, embed_i, embed_u, embed_r, wt, bias1p, cq, herr, h1u);

    if (big) {
        dense_fused<true><<<B_ / 2, 256, 0, stream>>>(nodes_v, neigh_u, neigh_r,
                                                      embed_u, embed_i, embed_r,
                                                      gv_b1, gv_b2, gv_b3, att_b2, att_w3,
                                                      wr1_b, wr2_b, wt, h1u, herr,
                                                      cq, bias1p, (float*)d_out);
    } else {
        dense_fused<false><<<B_ / 2, 256, 0, stream>>>(nodes_v, neigh_u, neigh_r,
                                                       embed_u, embed_i, embed_r,
                                                       gv_b1, gv_b2, gv_b3, att_b2, att_w3,
                                                       wr1_b, wr2_b, wt, h1u, herr,
                                                       cq, bias1p, (float*)d_out);
    }
}

// Round 7
// 160.792 us; speedup vs baseline: 1.1032x; 1.0482x over previous
//
#include <hip/hip_runtime.h>

typedef __bf16 bf16;
typedef short s16x8 __attribute__((ext_vector_type(8)));   // 8 bf16 bit-patterns for MFMA frags
typedef __bf16 b16x8 __attribute__((ext_vector_type(8)));  // 8 bf16 for scalar convert paths
typedef float f32x4 __attribute__((ext_vector_type(4)));

#define B_   4096
#define L_   50
#define SH   72               // H row stride (bf16): 64 + 8 pad (2-way bank alias, free)

// ws layout, bf16 elems. Frag-major matrices: frag f = kt*4+nt is a contiguous
// 512-elem (1 KB) block; elem = f*512 + lane*8 + j -> W[k=kt*32+(lane>>4)*8+j][n=nt*16+(lane&15)].
#define OFF_W1F  0            // gv_w1  frag-major, K=128 (16 frags)
#define OFF_W2F  8192         // gv_w2  frag-major, K=64 (8 frags)
#define OFF_W3F  12288        // gv_w3  frag-major
#define OFF_WCF  16384        // (gv_w3 @ att_w1_top) frag-major
#define OFF_A2F  20480        // att_w2 frag-major
#define OFF_R1T  24576        // [64][128] wr1^T row-major (combine tail per-lane dots)
#define OFF_R2T  32768        // [64][64]  wr2^T row-major
#define WT_TOTAL 36864
#define WL_ELEMS 24576        // LDS copy of [0, OFF_R1T): all 5 frag matrices, 48 KB
// byte offsets in ws:
#define BIAS1P_BYTE 73728     // float[64]        att_b1 + gv_b3 @ att_w1_top
#define CQ_BYTE     73984     // float[4096][64]  q_b @ A1_bot  (bias1p added in dense)
#define EU16_BYTE   1122560   // bf16[100000][64] embed_u pre-converted (RNE, same as mkfrag)
#define ER16_BYTE   13922560  // bf16[5][64]      embed_r pre-converted
#define WS_NEED     13923200

#define PREP_W_BLOCKS 145     // ceil((WT_TOTAL+64)/256)
#define CQ_BLOCKS     32      // 4096 items / (4 waves x 32 items) -- MFMA cq
#define CONV_THREADS  800040  // 100000*64/8 + 5*64/8
#define CONV_BLOCKS   3126    // ceil(CONV_THREADS/256)

#define DENSE_BLOCKS  512     // persistent: 2 blocks/CU, each handles 4 item-pairs
#define PAIRS_PER_BLK 4

__device__ __forceinline__ unsigned short f2b(float f) {
    __bf16 h = (__bf16)f;
    return __builtin_bit_cast(unsigned short, h);
}
__device__ __forceinline__ unsigned pack2(float a, float b) {
    return (unsigned)f2b(a) | ((unsigned)f2b(b) << 16);
}
__device__ __forceinline__ s16x8 mkfrag(float4 a, float4 b) {
    union { s16x8 v; unsigned u[4]; } r;
    r.u[0] = pack2(a.x, a.y); r.u[1] = pack2(a.z, a.w);
    r.u[2] = pack2(b.x, b.y); r.u[3] = pack2(b.z, b.w);
    return r.v;
}
__device__ __forceinline__ f32x4 mfma16(s16x8 a, s16x8 b, f32x4 c) {
    return __builtin_amdgcn_mfma_f32_16x16x32_bf16(a, b, c, 0, 0, 0);
}
__device__ __forceinline__ s16x8 ntload16(const bf16* p) {   // streaming gather: bypass L1 reuse
    return __builtin_nontemporal_load((const s16x8*)p);
}

// -------- prep (single launch): frag-major weights + bias1' + MFMA cq + bf16 embed tables -------
extern "C" __global__ void prep_all(const float* __restrict__ w1, const float* __restrict__ w2,
                                    const float* __restrict__ w3, const float* __restrict__ a1,
                                    const float* __restrict__ a2, const float* __restrict__ r1,
                                    const float* __restrict__ r2, const float* __restrict__ gb3,
                                    const float* __restrict__ ab1,
                                    const int* __restrict__ nodes_v, const float* __restrict__ embed_i,
                                    const float* __restrict__ embed_u, const float* __restrict__ embed_r,
                                    bf16* __restrict__ wt, float* __restrict__ bias1p,
                                    float* __restrict__ cq,
                                    bf16* __restrict__ eu16, bf16* __restrict__ er16)
{
    if (blockIdx.x >= PREP_W_BLOCKS + CQ_BLOCKS) {
        // bf16 conversion of the gather tables (identical RNE rounding to the dense mkfrag path)
        long t = (long)(blockIdx.x - PREP_W_BLOCKS - CQ_BLOCKS) * 256 + threadIdx.x;
        if (t < 800000) {
            const float* s = embed_u + t * 8;
            float4 a = *(const float4*)s, b = *(const float4*)(s + 4);
            *(s16x8*)(eu16 + t * 8) = mkfrag(a, b);
        } else if (t < CONV_THREADS) {
            long r = (t - 800000) * 8;
            const float* s = embed_r + r;
            float4 a = *(const float4*)s, b = *(const float4*)(s + 4);
            *(s16x8*)(er16 + r) = mkfrag(a, b);
        }
        return;
    }
    if (blockIdx.x >= PREP_W_BLOCKS) {
        // cq[i][n] = q_i @ A1_bot via MFMA: wave = 32 items (2 A-tiles), K=64, N=64.
        // B-frags built inline from a1 (L2-hot scalar loads) -> no dependence on wt (no race).
        int wv   = (blockIdx.x - PREP_W_BLOCKS) * 4 + (threadIdx.x >> 6);   // 0..127
        int lane = threadIdx.x & 63, m = lane & 15, quad = lane >> 4;
        int base = wv * 32;
        int i0 = base + m, i1 = base + 16 + m;
        int v0 = nodes_v[i0], v1 = nodes_v[i1];

        s16x8 bfr[8];
#pragma unroll
        for (int kt = 0; kt < 2; ++kt)
#pragma unroll
            for (int nt = 0; nt < 4; ++nt) {
                const float* src = a1 + (64 + kt * 32 + quad * 8) * 64 + nt * 16 + m;
                union { s16x8 v; unsigned u[4]; } fr;
#pragma unroll
                for (int jj = 0; jj < 4; ++jj)
                    fr.u[jj] = pack2(src[(2 * jj) * 64], src[(2 * jj + 1) * 64]);
                bfr[kt * 4 + nt] = fr.v;
            }

        f32x4 ac0[4] = {}, ac1[4] = {};
#pragma unroll
        for (int kt = 0; kt < 2; ++kt) {
            const float* q0 = embed_i + (size_t)v0 * 64 + kt * 32 + quad * 8;
            const float* q1 = embed_i + (size_t)v1 * 64 + kt * 32 + quad * 8;
            s16x8 aq0 = mkfrag(*(const float4*)q0, *(const float4*)(q0 + 4));
            s16x8 aq1 = mkfrag(*(const float4*)q1, *(const float4*)(q1 + 4));
#pragma unroll
            for (int nt = 0; nt < 4; ++nt) {
                ac0[nt] = mfma16(aq0, bfr[kt * 4 + nt], ac0[nt]);
                ac1[nt] = mfma16(aq1, bfr[kt * 4 + nt], ac1[nt]);
            }
        }
#pragma unroll
        for (int nt = 0; nt < 4; ++nt) {
            int c = nt * 16 + m;
#pragma unroll
            for (int r4 = 0; r4 < 4; ++r4) {
                cq[(base + quad * 4 + r4) * 64 + c]      = ac0[nt][r4];
                cq[(base + 16 + quad * 4 + r4) * 64 + c] = ac1[nt][r4];
            }
        }
        return;
    }
    int i = blockIdx.x * 256 + threadIdx.x;
    if (i >= WT_TOTAL + 64) return;
    if (i >= WT_TOTAL) {                       // bias1'[n] = ab1[n] + sum_t gb3[t]*a1[t][n]
        int n = i - WT_TOTAL;
        float s0 = ab1[n], s1 = 0.f, s2 = 0.f, s3 = 0.f;
#pragma unroll
        for (int t = 0; t < 64; t += 4) {
            s0 = fmaf(gb3[t],     a1[t * 64 + n],       s0);
            s1 = fmaf(gb3[t + 1], a1[(t + 1) * 64 + n], s1);
            s2 = fmaf(gb3[t + 2], a1[(t + 2) * 64 + n], s2);
            s3 = fmaf(gb3[t + 3], a1[(t + 3) * 64 + n], s3);
        }
        bias1p[n] = (s0 + s1) + (s2 + s3);
        return;
    }
    float val;
    if (i < OFF_R1T) {
        int off, kind;   // 0=w1,1=w2,2=w3,3=wca,4=a2
        if      (i < OFF_W2F) { off = OFF_W1F; kind = 0; }
        else if (i < OFF_W3F) { off = OFF_W2F; kind = 1; }
        else if (i < OFF_WCF) { off = OFF_W3F; kind = 2; }
        else if (i < OFF_A2F) { off = OFF_WCF; kind = 3; }
        else                  { off = OFF_A2F; kind = 4; }
        int local = i - off;
        int f = local >> 9, lane = (local >> 3) & 63, j = local & 7;
        int kt = f >> 2, nt = f & 3, quad = lane >> 4, m = lane & 15;
        int k = kt * 32 + quad * 8 + j;
        int n = nt * 16 + m;
        if (kind == 0)      val = w1[k * 64 + n];
        else if (kind == 1) val = w2[k * 64 + n];
        else if (kind == 2) val = w3[k * 64 + n];
        else if (kind == 4) val = a2[k * 64 + n];
        else {                                  // wca[k][n] = (W3 @ A1_top)[k][n]
            float s0 = 0.f, s1 = 0.f, s2 = 0.f, s3 = 0.f;
#pragma unroll
            for (int t = 0; t < 64; t += 4) {
                float4 w = *(const float4*)(w3 + k * 64 + t);
                s0 = fmaf(w.x, a1[t * 64 + n],       s0);
                s1 = fmaf(w.y, a1[(t + 1) * 64 + n], s1);
                s2 = fmaf(w.z, a1[(t + 2) * 64 + n], s2);
                s3 = fmaf(w.w, a1[(t + 3) * 64 + n], s3);
            }
            val = (s0 + s1) + (s2 + s3);
        }
    }
    else if (i < OFF_R2T) { int li = i - OFF_R1T; int n = li >> 7, k = li & 127; val = r1[k * 64 + n]; }
    else                  { int li = i - OFF_R2T; int n = li >> 6, k = li & 63;  val = r2[k * 64 + n]; }
    wt[i] = (bf16)val;
}

// -------- fused: PERSISTENT blocks. 512 blocks x 4 item-pairs; weights staged to LDS once; --------
// next pair's embedding gathers prefetched during current pair's compute (gather latency hidden
// under gv2..att2). Per-pair dataflow identical to the proven R2 structure (2 items x 64 rows,
// dual-tile waves, online-softmax partials, tail merge); 2 barriers per pair.
template<bool BF16E>
__global__ void __launch_bounds__(256, 2)
dense_fused(const int* __restrict__ nodes_v, const int* __restrict__ neigh_u,
            const int* __restrict__ neigh_r,
            const float* __restrict__ embed_u, const float* __restrict__ embed_i,
            const float* __restrict__ embed_r,
            const float* __restrict__ gv_b1, const float* __restrict__ gv_b2,
            const float* __restrict__ gv_b3,
            const float* __restrict__ att_b2, const float* __restrict__ att_w3,
            const float* __restrict__ wr1_b, const float* __restrict__ wr2_b,
            const bf16* __restrict__ wt, const bf16* __restrict__ eu16,
            const bf16* __restrict__ er16, const float* __restrict__ cq,
            const float* __restrict__ bias1p, float* __restrict__ out)
{
    __shared__ __align__(16) bf16 Wl[WL_ELEMS];     // 48 KB: all frag weights, staged once
    __shared__ __align__(16) bf16 H[128 * SH];      // 18.4 KB: h1 -> h2 -> att1h (same-wave reuse)
    __shared__ float zp[4 * 64];                    // per-wave e-weighted fjt partial S_w[64]
    __shared__ float swm[4 * 2];                    // per-wave {sum_e, max}
    __shared__ float qsh[2 * 64];                   // q per item (staged by tail wave)

    const int tid = threadIdx.x;
    const int lane = tid & 63, wave = tid >> 6;
    const int m = lane & 15, quad = lane >> 4;
    const int rw0 = wave * 32;                      // wave's rows in [0,128)
    const int item_w = rw0 >> 6;                    // this wave's item (0/1)
    const int lbase = rw0 & 63;                     // neighbor offset within item (0/32)

    // ---- stage ALL frag weights into LDS: 48 chunks x 1 KB, wave-uniform dest ----
    {
        const char* gsrc = (const char*)wt;
        char* ldst = (char*)Wl;
#pragma unroll
        for (int itc = 0; itc < 12; ++itc) {
            int ch = itc * 4 + wave;
            __builtin_amdgcn_global_load_lds(
                (const __attribute__((address_space(1))) void*)(gsrc + ch * 1024 + lane * 16),
                (__attribute__((address_space(3))) void*)(ldst + ch * 1024), 16, 0, 0);
        }
    }

    // iteration-invariant per-lane bias part
    float bp4[4];
#pragma unroll
    for (int nt = 0; nt < 4; ++nt) bp4[nt] = bias1p[nt * 16 + m];

    // ---- prefetch pair 0: A-frags (8 x 16B gathers) + cq rows ----
    s16x8 aC[8];        // [kt*2 + tile]: gv1 A-frags for this wave's 32 rows
    float cqv[4];
    {
        const int p = blockIdx.x * PAIRS_PER_BLK;
        const int bw = p * 2 + item_w;
        const int l0 = min(lbase + m, L_ - 1);
        const int l1 = min(lbase + 16 + m, L_ - 1);
        const int u0 = neigh_u[bw * L_ + l0], u1 = neigh_u[bw * L_ + l1];
        const int v0 = neigh_r[bw * L_ + l0], v1 = neigh_r[bw * L_ + l1];
        if constexpr (BF16E) {
            const bf16* p00 = eu16 + (size_t)u0 * 64;
            const bf16* p01 = eu16 + (size_t)u1 * 64;
            const bf16* p10 = er16 + (size_t)v0 * 64;
            const bf16* p11 = er16 + (size_t)v1 * 64;
#pragma unroll
            for (int kt = 0; kt < 4; ++kt) {
                aC[kt * 2]     = ntload16((kt < 2 ? p00 : p10) + (kt & 1) * 32 + quad * 8);
                aC[kt * 2 + 1] = ntload16((kt < 2 ? p01 : p11) + (kt & 1) * 32 + quad * 8);
            }
        } else {
            const float* b00 = embed_u + (size_t)u0 * 64;
            const float* b01 = embed_u + (size_t)u1 * 64;
            const float* b10 = embed_r + (size_t)v0 * 64;
            const float* b11 = embed_r + (size_t)v1 * 64;
#pragma unroll
            for (int kt = 0; kt < 4; ++kt) {
                const float* s0p = (kt < 2 ? b00 : b10) + (kt & 1) * 32 + quad * 8;
                const float* s1p = (kt < 2 ? b01 : b11) + (kt & 1) * 32 + quad * 8;
                aC[kt * 2]     = mkfrag(*(const float4*)s0p, *(const float4*)(s0p + 4));
                aC[kt * 2 + 1] = mkfrag(*(const float4*)s1p, *(const float4*)(s1p + 4));
            }
        }
#pragma unroll
        for (int nt = 0; nt < 4; ++nt) cqv[nt] = cq[bw * 64 + nt * 16 + m];
    }

    __syncthreads();   // staging fence: compiler drains vmcnt before s_barrier -> Wl + aC ready

    bf16* H0 = H + rw0 * SH;   // this wave's 32 rows (tile 0)
    bf16* H1 = H0 + 16 * SH;   // tile 1

#pragma unroll 1
    for (int it = 0; it < PAIRS_PER_BLK; ++it) {
        const int p  = blockIdx.x * PAIRS_PER_BLK + it;
        const int b0 = p * 2;
        const int bw = b0 + item_w;

        float cs4[4];
#pragma unroll
        for (int nt = 0; nt < 4; ++nt) cs4[nt] = cqv[nt] + bp4[nt];

        // ---- gv1: h1 = relu([pt|er] @ W1 + b1) -> H  (A-frags prefetched) ----
        {
            f32x4 ac0[4] = {}, ac1[4] = {};
#pragma unroll
            for (int kt = 0; kt < 4; ++kt) {
                s16x8 a0 = aC[kt * 2], a1 = aC[kt * 2 + 1];
#pragma unroll
                for (int nt = 0; nt < 4; ++nt) {
                    s16x8 bfr = *(const s16x8*)(Wl + OFF_W1F + (kt * 4 + nt) * 512 + lane * 8);
                    ac0[nt] = mfma16(a0, bfr, ac0[nt]);
                    ac1[nt] = mfma16(a1, bfr, ac1[nt]);
                }
            }
#pragma unroll
            for (int nt = 0; nt < 4; ++nt) {
                int c = nt * 16 + m;
                float bv = gv_b1[c];
#pragma unroll
                for (int r4 = 0; r4 < 4; ++r4) {
                    H0[(quad * 4 + r4) * SH + c] = (bf16)fmaxf(ac0[nt][r4] + bv, 0.f);
                    H1[(quad * 4 + r4) * SH + c] = (bf16)fmaxf(ac1[nt][r4] + bv, 0.f);
                }
            }
        }

        // ---- prefetch NEXT pair's gathers + cq (overlaps gv2..att2; aC is dead after gv1) ----
        if (it + 1 < PAIRS_PER_BLK) {
            const int bwN = (p + 1) * 2 + item_w;
            const int l0 = min(lbase + m, L_ - 1);
            const int l1 = min(lbase + 16 + m, L_ - 1);
            const int u0 = neigh_u[bwN * L_ + l0], u1 = neigh_u[bwN * L_ + l1];
            const int v0 = neigh_r[bwN * L_ + l0], v1 = neigh_r[bwN * L_ + l1];
            if constexpr (BF16E) {
                const bf16* p00 = eu16 + (size_t)u0 * 64;
                const bf16* p01 = eu16 + (size_t)u1 * 64;
                const bf16* p10 = er16 + (size_t)v0 * 64;
                const bf16* p11 = er16 + (size_t)v1 * 64;
#pragma unroll
                for (int kt = 0; kt < 4; ++kt) {
                    aC[kt * 2]     = ntload16((kt < 2 ? p00 : p10) + (kt & 1) * 32 + quad * 8);
                    aC[kt * 2 + 1] = ntload16((kt < 2 ? p01 : p11) + (kt & 1) * 32 + quad * 8);
                }
            } else {
                const float* b00 = embed_u + (size_t)u0 * 64;
                const float* b01 = embed_u + (size_t)u1 * 64;
                const float* b10 = embed_r + (size_t)v0 * 64;
                const float* b11 = embed_r + (size_t)v1 * 64;
#pragma unroll
                for (int kt = 0; kt < 4; ++kt) {
                    const float* s0p = (kt < 2 ? b00 : b10) + (kt & 1) * 32 + quad * 8;
                    const float* s1p = (kt < 2 ? b01 : b11) + (kt & 1) * 32 + quad * 8;
                    aC[kt * 2]     = mkfrag(*(const float4*)s0p, *(const float4*)(s0p + 4));
                    aC[kt * 2 + 1] = mkfrag(*(const float4*)s1p, *(const float4*)(s1p + 4));
                }
            }
#pragma unroll
            for (int nt = 0; nt < 4; ++nt) cqv[nt] = cq[bwN * 64 + nt * 16 + m];
        }

        // ---- gv2: h1 -> h2 (in-place, same-wave WAR safe); frags from LDS ----
        {
            f32x4 ac0[4] = {}, ac1[4] = {};
#pragma unroll
            for (int kt = 0; kt < 2; ++kt) {
                s16x8 a0 = *(const s16x8*)(H0 + m * SH + kt * 32 + quad * 8);
                s16x8 a1 = *(const s16x8*)(H1 + m * SH + kt * 32 + quad * 8);
#pragma unroll
                for (int nt = 0; nt < 4; ++nt) {
                    s16x8 bfr = *(const s16x8*)(Wl + OFF_W2F + (kt * 4 + nt) * 512 + lane * 8);
                    ac0[nt] = mfma16(a0, bfr, ac0[nt]);
                    ac1[nt] = mfma16(a1, bfr, ac1[nt]);
                }
            }
#pragma unroll
            for (int nt = 0; nt < 4; ++nt) {
                int c = nt * 16 + m;
                float bv = gv_b2[c];
#pragma unroll
                for (int r4 = 0; r4 < 4; ++r4) {
                    H0[(quad * 4 + r4) * SH + c] = (bf16)fmaxf(ac0[nt][r4] + bv, 0.f);
                    H1[(quad * 4 + r4) * SH + c] = (bf16)fmaxf(ac1[nt][r4] + bv, 0.f);
                }
            }
        }

        // ---- fused gv3 + att1': consume h2; fjt stays in regs (aF), att1h -> H ----
        f32x4 aF0[4] = {}, aF1[4] = {};
        {
            f32x4 aA0[4] = {}, aA1[4] = {};
#pragma unroll
            for (int kt = 0; kt < 2; ++kt) {
                s16x8 a0 = *(const s16x8*)(H0 + m * SH + kt * 32 + quad * 8);
                s16x8 a1 = *(const s16x8*)(H1 + m * SH + kt * 32 + quad * 8);
#pragma unroll
                for (int nt = 0; nt < 4; ++nt) {
                    s16x8 bF = *(const s16x8*)(Wl + OFF_W3F + (kt * 4 + nt) * 512 + lane * 8);
                    s16x8 bA = *(const s16x8*)(Wl + OFF_WCF + (kt * 4 + nt) * 512 + lane * 8);
                    aF0[nt] = mfma16(a0, bF, aF0[nt]);
                    aF1[nt] = mfma16(a1, bF, aF1[nt]);
                    aA0[nt] = mfma16(a0, bA, aA0[nt]);
                    aA1[nt] = mfma16(a1, bA, aA1[nt]);
                }
            }
            // write only att1h; aF kept in regs (gv_b3 folded into zj via sum(mu)==1)
#pragma unroll
            for (int nt = 0; nt < 4; ++nt) {
                int c = nt * 16 + m;
#pragma unroll
                for (int r4 = 0; r4 < 4; ++r4) {
                    H0[(quad * 4 + r4) * SH + c] = (bf16)fmaxf(aA0[nt][r4] + cs4[nt], 0.f);
                    H1[(quad * 4 + r4) * SH + c] = (bf16)fmaxf(aA1[nt][r4] + cs4[nt], 0.f);
                }
            }
        }

        // ---- att2 + relu + dot(att_w3) + m-reduce -> per-row scores in regs ----
        float s0[4], s1[4];
        {
            f32x4 ac0[4] = {}, ac1[4] = {};
#pragma unroll
            for (int kt = 0; kt < 2; ++kt) {
                s16x8 a0 = *(const s16x8*)(H0 + m * SH + kt * 32 + quad * 8);
                s16x8 a1 = *(const s16x8*)(H1 + m * SH + kt * 32 + quad * 8);
#pragma unroll
                for (int nt = 0; nt < 4; ++nt) {
                    s16x8 bfr = *(const s16x8*)(Wl + OFF_A2F + (kt * 4 + nt) * 512 + lane * 8);
                    ac0[nt] = mfma16(a0, bfr, ac0[nt]);
                    ac1[nt] = mfma16(a1, bfr, ac1[nt]);
                }
            }
#pragma unroll
            for (int r4 = 0; r4 < 4; ++r4) { s0[r4] = 0.f; s1[r4] = 0.f; }
#pragma unroll
            for (int nt = 0; nt < 4; ++nt) {
                int c = nt * 16 + m;
                float b2v = att_b2[c], w3v = att_w3[c];
#pragma unroll
                for (int r4 = 0; r4 < 4; ++r4) {
                    s0[r4] += fmaxf(ac0[nt][r4] + b2v, 0.f) * w3v;
                    s1[r4] += fmaxf(ac1[nt][r4] + b2v, 0.f) * w3v;
                }
            }
#pragma unroll
            for (int mask = 1; mask < 16; mask <<= 1)
#pragma unroll
                for (int r4 = 0; r4 < 4; ++r4) {
                    s0[r4] += __shfl_xor(s0[r4], mask);
                    s1[r4] += __shfl_xor(s1[r4], mask);
                }
        }

        // ---- per-wave ONLINE-softmax partial over this wave's 32 rows ----
        {
            const int r0b = lbase + quad * 4;
            float mloc = -1e30f;
#pragma unroll
            for (int r4 = 0; r4 < 4; ++r4) {
                if (r0b + r4 < L_)      mloc = fmaxf(mloc, s0[r4]);
                if (r0b + 16 + r4 < L_) mloc = fmaxf(mloc, s1[r4]);
            }
            mloc = fmaxf(mloc, __shfl_xor(mloc, 16));
            mloc = fmaxf(mloc, __shfl_xor(mloc, 32));

            float e0[4], e1[4], ssum = 0.f;
#pragma unroll
            for (int r4 = 0; r4 < 4; ++r4) {
                e0[r4] = (r0b + r4 < L_)      ? __expf(s0[r4] - mloc) : 0.f;
                e1[r4] = (r0b + 16 + r4 < L_) ? __expf(s1[r4] - mloc) : 0.f;
                ssum += e0[r4] + e1[r4];
            }
            ssum += __shfl_xor(ssum, 16);
            ssum += __shfl_xor(ssum, 32);

            float z[4] = {0.f, 0.f, 0.f, 0.f};
#pragma unroll
            for (int r4 = 0; r4 < 4; ++r4)
#pragma unroll
                for (int nt = 0; nt < 4; ++nt)
                    z[nt] += aF0[nt][r4] * e0[r4] + aF1[nt][r4] * e1[r4];
#pragma unroll
            for (int nt = 0; nt < 4; ++nt) {
                z[nt] += __shfl_xor(z[nt], 16);
                z[nt] += __shfl_xor(z[nt], 32);
            }
            if (quad == 0) {
#pragma unroll
                for (int nt = 0; nt < 4; ++nt) zp[wave * 64 + nt * 16 + m] = z[nt];
            }
            if (lane == 0) { swm[wave * 2] = ssum; swm[wave * 2 + 1] = mloc; }
        }
        __syncthreads();   // partials ready for tail

        // ---- tail: wave 0 -> item 0, wave 2 -> item 1 (merge + combine MLP) ----
        if ((wave & 1) == 0) {
            const int item = wave >> 1;
            const int d = lane;
            float ma = swm[wave * 2 + 1],      mb = swm[(wave + 1) * 2 + 1];
            float sa = swm[wave * 2],          sb = swm[(wave + 1) * 2];
            float M  = fmaxf(ma, mb);
            float fa = __expf(ma - M), fb = __expf(mb - M);
            float zj = (fa * zp[wave * 64 + d] + fb * zp[(wave + 1) * 64 + d])
                     / (fa * sa + fb * sb) + gv_b3[d];

            float* zsh = zp + wave * 64;
            zsh[d] = zj;
            qsh[item * 64 + d] = embed_i[(size_t)nodes_v[b0 + item] * 64 + d];

            // z2 = relu([zj|q] @ wr1 + b1)
            float accz = wr1_b[d];
            const bf16* r1 = wt + OFF_R1T + d * 128;
#pragma unroll
            for (int k8 = 0; k8 < 8; ++k8) {
                b16x8 wv = *(const b16x8*)(r1 + k8 * 8);
#pragma unroll
                for (int j = 0; j < 8; ++j) accz = fmaf((float)wv[j], zsh[k8 * 8 + j], accz);
            }
#pragma unroll
            for (int k8 = 0; k8 < 8; ++k8) {
                b16x8 wv = *(const b16x8*)(r1 + 64 + k8 * 8);
#pragma unroll
                for (int j = 0; j < 8; ++j) accz = fmaf((float)wv[j], qsh[item * 64 + k8 * 8 + j], accz);
            }
            zsh[d] = fmaxf(accz, 0.f);

            // out = relu(z2 @ wr2 + b2)
            float acco = wr2_b[d];
            const bf16* r2 = wt + OFF_R2T + d * 64;
#pragma unroll
            for (int k8 = 0; k8 < 8; ++k8) {
                b16x8 wv = *(const b16x8*)(r2 + k8 * 8);
#pragma unroll
                for (int j = 0; j < 8; ++j) acco = fmaf((float)wv[j], zsh[k8 * 8 + j], acco);
            }
            out[(size_t)(b0 + item) * 64 + d] = fmaxf(acco, 0.f);
        }
        __syncthreads();   // zp/swm/qsh free for next pair
    }
}

extern "C" void kernel_launch(void* const* d_in, const int* in_sizes, int n_in,
                              void* d_out, int out_size, void* d_ws, size_t ws_size,
                              hipStream_t stream)
{
    const int* nodes_v = (const int*)d_in[0];
    const int* neigh_u = (const int*)d_in[1];
    const int* neigh_r = (const int*)d_in[2];
    const float* embed_u = (const float*)d_in[3];
    const float* embed_i = (const float*)d_in[4];
    const float* embed_r = (const float*)d_in[5];
    const float* gv_w1  = (const float*)d_in[6];  const float* gv_b1 = (const float*)d_in[7];
    const float* gv_w2  = (const float*)d_in[8];  const float* gv_b2 = (const float*)d_in[9];
    const float* gv_w3  = (const float*)d_in[10]; const float* gv_b3 = (const float*)d_in[11];
    const float* att_w1 = (const float*)d_in[12]; const float* att_b1 = (const float*)d_in[13];
    const float* att_w2 = (const float*)d_in[14]; const float* att_b2 = (const float*)d_in[15];
    const float* att_w3 = (const float*)d_in[16]; const float* att_b3 = (const float*)d_in[17];
    const float* wr1_w  = (const float*)d_in[18]; const float* wr1_b = (const float*)d_in[19];
    const float* wr2_w  = (const float*)d_in[20]; const float* wr2_b = (const float*)d_in[21];
    (void)att_b3;  // softmax shift-invariance

    bf16*  wt     = (bf16*)d_ws;
    float* bias1p = (float*)((char*)d_ws + BIAS1P_BYTE);
    float* cq     = (float*)((char*)d_ws + CQ_BYTE);
    bf16*  eu16   = (bf16*)((char*)d_ws + EU16_BYTE);
    bf16*  er16   = (bf16*)((char*)d_ws + ER16_BYTE);

    const bool big = ws_size >= (size_t)WS_NEED;
    const int prep_grid = PREP_W_BLOCKS + CQ_BLOCKS + (big ? CONV_BLOCKS : 0);

    prep_all<<<prep_grid, 256, 0, stream>>>(
        gv_w1, gv_w2, gv_w3, att_w1, att_w2, wr1_w, wr2_w, gv_b3, att_b1,
        nodes_v, embed_i, embed_u, embed_r, wt, bias1p, cq, eu16, er16);

    if (big) {
        dense_fused<true><<<DENSE_BLOCKS, 256, 0, stream>>>(nodes_v, neigh_u, neigh_r,
                                                            embed_u, embed_i, embed_r,
                                                            gv_b1, gv_b2, gv_b3, att_b2, att_w3,
                                                            wr1_b, wr2_b, wt, eu16, er16,
                                                            cq, bias1p, (float*)d_out);
    } else {
        dense_fused<false><<<DENSE_BLOCKS, 256, 0, stream>>>(nodes_v, neigh_u, neigh_r,
                                                             embed_u, embed_i, embed_r,
                                                             gv_b1, gv_b2, gv_b3, att_b2, att_w3,
                                                             wr1_b, wr2_b, wt, eu16, er16,
                                                             cq, bias1p, (float*)d_out);
    }
}